// Round 12
// baseline (317.968 us; speedup 1.0000x reference)
//
#include <hip/hip_runtime.h>

// R12 = R9 resubmit (infra failures x6). R8 main kernel (unchanged, 63us) +
// two bandwidth probe dispatches to resolve whether the ~2.4 TB/s plateau
// (identical across 3 structurally different kernels in R1/R2/R8) is
// kernel-side or this box's achievable ceiling. Probes run BEFORE the main
// kernel; bw_copy_probe scribbles on d_out, which the main kernel then fully
// rewrites -> output still correct.

#define TPB 256
#define GPB 512               // gaussians per block
#define SC_SLOTS 384          // 512*3 floats  = 384 float4
#define ROT_SLOTS 512         // 512*4 floats  = 512 float4
#define OUT_SLOTS 768         // 512*6 floats  = 768 float4

typedef float f32x4 __attribute__((ext_vector_type(4)));

// ---------------- BW probes (diagnostic, this round only) ----------------

__global__ __launch_bounds__(256) void bw_read_probe(
    const f32x4* __restrict__ src, long long n4)
{
    long long stride = (long long)gridDim.x * 256;
    f32x4 acc = {0.f, 0.f, 0.f, 0.f};
    #pragma unroll 1
    for (int p = 0; p < 8; ++p) {
        for (long long i = (long long)blockIdx.x * 256 + threadIdx.x; i < n4; i += stride) {
            f32x4 v = src[i];
            acc += v;
        }
        // force acc to be materialized each pass: blocks cross-pass CSE
        asm volatile("" : "+v"(acc.x), "+v"(acc.y), "+v"(acc.z), "+v"(acc.w));
    }
    float r = acc.x + acc.y + acc.z + acc.w;
    asm volatile("" :: "v"(r));   // sink: keep all loads live, no global write
}

__global__ __launch_bounds__(256) void bw_copy_probe(
    const f32x4* __restrict__ src, f32x4* __restrict__ dst, long long n4)
{
    long long stride = (long long)gridDim.x * 256;
    #pragma unroll 1
    for (int p = 0; p < 4; ++p) {
        float scale = (float)(p + 1);             // pass-varying value: defeats
        for (long long i = (long long)blockIdx.x * 256 + threadIdx.x; i < n4; i += stride) {
            f32x4 v = src[i] * scale;             // store-sinking / cross-pass DSE
            __builtin_nontemporal_store(v, &dst[i]);
        }
    }
}

// ---------------- main kernel: identical to R8 ----------------

__device__ __forceinline__ void cov6(float w, float x, float y, float z,
                                     float s0, float s1, float s2,
                                     float* __restrict__ c) {
    float inv = rsqrtf(w * w + x * x + y * y + z * z);
    w *= inv; x *= inv; y *= inv; z *= inv;
    float xx = x * x, yy = y * y, zz = z * z;
    float xy = x * y, xz = x * z, yz = y * z;
    float wx = w * x, wy = w * y, wz = w * z;
    float L00 = (1.f - 2.f * (yy + zz)) * s0, L01 = 2.f * (xy - wz) * s1, L02 = 2.f * (xz + wy) * s2;
    float L10 = 2.f * (xy + wz) * s0, L11 = (1.f - 2.f * (xx + zz)) * s1, L12 = 2.f * (yz - wx) * s2;
    float L20 = 2.f * (xz - wy) * s0, L21 = 2.f * (yz + wx) * s1, L22 = (1.f - 2.f * (xx + yy)) * s2;
    c[0] = L00 * L00 + L01 * L01 + L02 * L02;
    c[1] = L00 * L10 + L01 * L11 + L02 * L12;
    c[2] = L00 * L20 + L01 * L21 + L02 * L22;
    c[3] = L10 * L10 + L11 * L11 + L12 * L12;
    c[4] = L10 * L20 + L11 * L21 + L12 * L22;
    c[5] = L20 * L20 + L21 * L21 + L22 * L22;
}

__global__ __launch_bounds__(TPB, 8) void gauss_cov_lds(
    const float4* __restrict__ sr4,   // scaling_raw as N*3/4 float4
    const float4* __restrict__ rot4,  // rotation as N float4
    float4* __restrict__ out4,        // out as N*6/4 float4
    int n)
{
    __shared__ float4 lds[SC_SLOTS + ROT_SLOTS];   // 896 * 16 B = 14336 B
    const int tid = threadIdx.x;

    const long long sc_total  = (long long)n * 3 / 4;
    const long long out_total = (long long)n * 6 / 4;

    // ---- stage: perfectly coalesced global float4 loads -> LDS ----
    {
        const long long sb = (long long)blockIdx.x * SC_SLOTS;
        #pragma unroll
        for (int k = 0; k < 2; ++k) {            // 384 slots
            int j = tid + k * TPB;
            if (j < SC_SLOTS && sb + j < sc_total)
                lds[j] = sr4[sb + j];
        }
        const long long rb = (long long)blockIdx.x * GPB;
        #pragma unroll
        for (int k = 0; k < 2; ++k) {            // 512 slots; source pre-swizzled
            int j = tid + k * TPB;
            int js = j ^ ((j >> 3) & 7);         // XOR involution within 512-window
            if (rb + js < (long long)n)
                lds[SC_SLOTS + j] = rot4[rb + js];
        }
    }
    __syncthreads();

    // ---- gather my 2 gaussians from LDS ----
    const float* ldsf = (const float*)lds;
    float2 sa = *(const float2*)(ldsf + 6 * tid);      // 8B-aligned (24t)
    float2 sbv = *(const float2*)(ldsf + 6 * tid + 2);
    float2 sc = *(const float2*)(ldsf + 6 * tid + 4);
    int r0 = 2 * tid, r1 = 2 * tid + 1;
    float4 q0 = lds[SC_SLOTS + (r0 ^ ((r0 >> 3) & 7))];  // swizzled -> bank-minimal
    float4 q1 = lds[SC_SLOTS + (r1 ^ ((r1 >> 3) & 7))];
    __syncthreads();   // all input reads done; LDS reusable for output

    // ---- compute (registers only) ----
    float e0 = __expf(sa.x), e1 = __expf(sa.y), e2 = __expf(sbv.x);
    float e3 = __expf(sbv.y), e4 = __expf(sc.x), e5 = __expf(sc.y);
    float c[12];
    cov6(q0.x, q0.y, q0.z, q0.w, e0, e1, e2, c);
    cov6(q1.x, q1.y, q1.z, q1.w, e3, e4, e5, c + 6);

    // ---- scatter to LDS (float4-aligned, bank-balanced), then coalesced store ----
    float* outf = (float*)lds;
    *(float4*)(outf + 12 * tid + 0) = make_float4(c[0], c[1], c[2],  c[3]);
    *(float4*)(outf + 12 * tid + 4) = make_float4(c[4], c[5], c[6],  c[7]);
    *(float4*)(outf + 12 * tid + 8) = make_float4(c[8], c[9], c[10], c[11]);
    __syncthreads();

    const long long ob = (long long)blockIdx.x * OUT_SLOTS;
    const f32x4* ldsn = (const f32x4*)lds;
    f32x4* outn = (f32x4*)out4;
    #pragma unroll
    for (int k = 0; k < 3; ++k) {                // 768 slots
        int j = tid + k * TPB;
        if (ob + j < out_total)
            __builtin_nontemporal_store(ldsn[j], &outn[ob + j]);
    }
}

extern "C" void kernel_launch(void* const* d_in, const int* in_sizes, int n_in,
                              void* d_out, int out_size, void* d_ws, size_t ws_size,
                              hipStream_t stream) {
    const float4* sr4  = (const float4*)d_in[0];  // (N,3) f32
    const float4* rot4 = (const float4*)d_in[1];  // (N,4) f32
    float4* out4 = (float4*)d_out;                // (N,6) f32
    int n = in_sizes[0] / 3;
    long long rot_n4 = (long long)in_sizes[1] / 4;   // rotation as float4 count

    // --- diagnostic probes first (copy probe scribbles d_out; main rewrites) ---
    bw_read_probe<<<2048, 256, 0, stream>>>((const f32x4*)rot4, rot_n4);
    long long copy_n4 = rot_n4;                       // 64 MB <= 96 MB out buffer
    if (copy_n4 * 4 > out_size) copy_n4 = out_size / 4;
    bw_copy_probe<<<2048, 256, 0, stream>>>((const f32x4*)rot4, (f32x4*)d_out, copy_n4);

    // --- main kernel (must run LAST: rewrites all of d_out) ---
    int grid = (int)(((long long)n + GPB - 1) / GPB);
    gauss_cov_lds<<<grid, TPB, 0, stream>>>(sr4, rot4, out4, n);
}